// Round 1
// baseline (348.608 us; speedup 1.0000x reference)
//
#include <hip/hip_runtime.h>
#include <hip/hip_bf16.h>

// RGBRenderer: out[ray][c] = sum_s w_s * rgb[ray][s][c]
//   dd_s   = deltas[ray][s] * density[ray][s]
//   cum_s  = exclusive cumsum of dd  (cum_0 = 0)
//   w_s    = (1 - exp(-dd_s)) * exp(-cum_s) = exp(-cum_s) - exp(-cum_{s+1})
//
// One wave (64 lanes) per ray, 4 samples per lane. All loads float4-coalesced.

#define N_RAYS 65536
#define N_SAMPLES 256

__global__ __launch_bounds__(256) void rgb_render_kernel(
    const float* __restrict__ rgb,      // [N_RAYS, 256, 3]
    const float* __restrict__ density,  // [N_RAYS, 256]
    const float* __restrict__ deltas,   // [N_RAYS, 256]
    float* __restrict__ out)            // [N_RAYS, 3]
{
    const int lane = threadIdx.x & 63;
    const int wave_in_block = threadIdx.x >> 6;
    const int ray = blockIdx.x * (blockDim.x >> 6) + wave_in_block;

    // ---- load deltas & density: 4 contiguous samples per lane (float4) ----
    const float4* d4 = (const float4*)(deltas  + (size_t)ray * N_SAMPLES);
    const float4* s4 = (const float4*)(density + (size_t)ray * N_SAMPLES);
    float4 de = d4[lane];
    float4 si = s4[lane];

    float dd0 = de.x * si.x;
    float dd1 = de.y * si.y;
    float dd2 = de.z * si.z;
    float dd3 = de.w * si.w;

    // local inclusive prefix within the lane's 4 samples
    float p1 = dd0 + dd1;
    float p2 = p1 + dd2;
    float p3 = p2 + dd3;          // lane total

    // ---- wave-level inclusive scan of lane totals (64 lanes) ----
    float x = p3;
    #pragma unroll
    for (int off = 1; off < 64; off <<= 1) {
        float y = __shfl_up(x, off, 64);
        if (lane >= off) x += y;
    }
    float excl = x - p3;          // exclusive cumsum at this lane's first sample

    // ---- transmittance at the 5 sample boundaries, weights by telescoping ----
    float t0 = __expf(-excl);
    float t1 = __expf(-(excl + dd0));
    float t2 = __expf(-(excl + p1));
    float t3 = __expf(-(excl + p2));
    float t4 = __expf(-(excl + p3));
    float w0 = t0 - t1;
    float w1 = t1 - t2;
    float w2 = t2 - t3;
    float w3 = t3 - t4;

    // ---- rgb: 12 contiguous floats per lane = 3x float4 (48B, 16B-aligned) ----
    const float4* r4 = (const float4*)(rgb + (size_t)ray * (N_SAMPLES * 3) + lane * 12);
    float4 a = r4[0];
    float4 b = r4[1];
    float4 c = r4[2];
    // sample0: a.x a.y a.z | sample1: a.w b.x b.y | sample2: b.z b.w c.x | sample3: c.y c.z c.w
    float rr = w0 * a.x + w1 * a.w + w2 * b.z + w3 * c.y;
    float gg = w0 * a.y + w1 * b.x + w2 * b.w + w3 * c.z;
    float bb = w0 * a.z + w1 * b.y + w2 * c.x + w3 * c.w;

    // ---- wave reduction over 64 lanes ----
    #pragma unroll
    for (int off = 32; off > 0; off >>= 1) {
        rr += __shfl_down(rr, off, 64);
        gg += __shfl_down(gg, off, 64);
        bb += __shfl_down(bb, off, 64);
    }

    if (lane == 0) {
        float* o = out + (size_t)ray * 3;
        o[0] = rr;
        o[1] = gg;
        o[2] = bb;
    }
}

extern "C" void kernel_launch(void* const* d_in, const int* in_sizes, int n_in,
                              void* d_out, int out_size, void* d_ws, size_t ws_size,
                              hipStream_t stream) {
    const float* rgb     = (const float*)d_in[0];
    const float* density = (const float*)d_in[1];
    const float* deltas  = (const float*)d_in[2];
    float* out = (float*)d_out;

    // 4 rays per 256-thread block (one wave per ray)
    dim3 block(256);
    dim3 grid(N_RAYS / 4);
    rgb_render_kernel<<<grid, block, 0, stream>>>(rgb, density, deltas, out);
}

// Round 2
// 301.571 us; speedup vs baseline: 1.1560x; 1.1560x over previous
//
#include <hip/hip_runtime.h>
#include <hip/hip_bf16.h>

// RGBRenderer: out[ray][c] = sum_s w_s * rgb[ray][s][c]
//   dd_s  = deltas[ray][s] * density[ray][s]
//   w_s   = exp(-cum_s) - exp(-cum_{s+1})   (telescoped, cum = exclusive cumsum)
//
// One wave per ray. Samples processed in chunks of 64 (1 sample/lane).
// Early exit: once running optical depth > 13.8 (T < 1e-6), remaining samples
// contribute <= 1e-6 total (rgb in [0,1], sum of remaining w <= T) -- 4 orders
// of magnitude under the 1.8e-2 pass threshold. With U(0,1) inputs the cutoff
// lands near sample ~48, so ~1 chunk of 4 runs on almost every ray.
// Per-lane rgb loads are predicated on T_start > 1e-6 (same bound), and are
// float3 (dwordx3, 12 B/lane contiguous) -- fully coalesced.

#define N_RAYS 65536
#define N_SAMPLES 256

__global__ __launch_bounds__(256) void rgb_render_kernel(
    const float* __restrict__ rgb,      // [N_RAYS, 256, 3]
    const float* __restrict__ density,  // [N_RAYS, 256]
    const float* __restrict__ deltas,   // [N_RAYS, 256]
    float* __restrict__ out)            // [N_RAYS, 3]
{
    const int lane = threadIdx.x & 63;
    const int ray  = (int)((blockIdx.x * blockDim.x + threadIdx.x) >> 6);

    const float*  dl = deltas  + (size_t)ray * N_SAMPLES;
    const float*  dn = density + (size_t)ray * N_SAMPLES;
    const float3* r3 = (const float3*)(rgb + (size_t)ray * (N_SAMPLES * 3));

    float run = 0.0f;                 // optical depth consumed by prior chunks (uniform)
    float rr = 0.0f, gg = 0.0f, bb = 0.0f;

    #pragma unroll 1
    for (int c = 0; c < N_SAMPLES / 64; ++c) {
        const int s = c * 64 + lane;
        float dd = dl[s] * dn[s];

        // wave-inclusive scan of dd (64 lanes)
        float x = dd;
        #pragma unroll
        for (int off = 1; off < 64; off <<= 1) {
            float y = __shfl_up(x, off, 64);
            if (lane >= off) x += y;
        }

        const float incl = run + x;        // cum after this sample
        const float excl = incl - dd;      // cum before this sample
        const float Ts = __expf(-excl);    // transmittance entering this sample
        const float w  = Ts - __expf(-incl);

        if (Ts > 1e-6f) {                  // skipped lanes: contribution <= 1e-6
            float3 v = r3[s];
            rr = fmaf(w, v.x, rr);
            gg = fmaf(w, v.y, gg);
            bb = fmaf(w, v.z, bb);
        }

        run += __shfl(x, 63, 64);          // chunk total, uniform broadcast
        if (run > 13.8f) break;            // T < 1e-6: rest of ray is negligible
    }

    // wave reduction of the 3 channel partials
    #pragma unroll
    for (int off = 32; off > 0; off >>= 1) {
        rr += __shfl_down(rr, off, 64);
        gg += __shfl_down(gg, off, 64);
        bb += __shfl_down(bb, off, 64);
    }

    if (lane == 0) {
        float* o = out + (size_t)ray * 3;
        o[0] = rr;
        o[1] = gg;
        o[2] = bb;
    }
}

extern "C" void kernel_launch(void* const* d_in, const int* in_sizes, int n_in,
                              void* d_out, int out_size, void* d_ws, size_t ws_size,
                              hipStream_t stream) {
    const float* rgb     = (const float*)d_in[0];
    const float* density = (const float*)d_in[1];
    const float* deltas  = (const float*)d_in[2];
    float* out = (float*)d_out;

    // one wave per ray, 4 waves per block
    dim3 block(256);
    dim3 grid(N_RAYS / 4);
    rgb_render_kernel<<<grid, block, 0, stream>>>(rgb, density, deltas, out);
}